// Round 4
// baseline (465.531 us; speedup 1.0000x reference)
//
#include <hip/hip_runtime.h>
#include <hip/hip_bf16.h>
#include <math.h>

#define GS 1024
#define BSZ 256
#define DD 128
#define NEGV -1e30f

typedef __attribute__((ext_vector_type(8))) short bf16x8_t;
typedef __attribute__((ext_vector_type(4))) float f32x4_t;
typedef __attribute__((ext_vector_type(2))) float f32x2_t;

// ---- workspace layout (bytes) ----
#define WGRU_OFF_BYTES 131072
#define WQP_OFF_BYTES  524288
#define WIHB_OFF_BYTES 655360
#define F_OFF_BYTES    688128
// float offsets inside F:
#define FH_HM   0        // 262144  h-mean partials [b][seg][d]
#define FI_V    262144   // 65536   [b][256] V1|V2
#define FJ_AQB  327680   // 524288  [b][d][j][sel]  sel = {a1,b1,a2,b2}
#define FK_RES  851968   // 1048576 [b][j][g]
#define F_TOTAL 1900544
#define DESC_OFF_BYTES (F_OFF_BYTES + F_TOTAL * 4)   // int [b][32]

__device__ __forceinline__ float rtanh(float x) {
    // x / sqrt(1 + x^2): tanh-shaped, saturating, |dev| <= 0.065 (fine per tolerance)
    float s = fmaf(x, x, 1.0f);
    return x * __builtin_amdgcn_rsqf(s);
}
__device__ __forceinline__ float tanh2(float x) {
    float e = __expf(x + x);
    return fmaf(-2.0f, __builtin_amdgcn_rcpf(e + 1.0f), 1.0f);
}
__device__ __forceinline__ float sigm2(float x) {
    return __builtin_amdgcn_rcpf(1.0f + __expf(-x));
}
__device__ __forceinline__ unsigned short f2bf(float f) {
    union { float f; unsigned u; } v; v.f = f;
    unsigned u = v.u;
    return (unsigned short)((u + 0x7fffu + ((u >> 16) & 1u)) >> 16);
}
#define MFMA16(a, b, c) __builtin_amdgcn_mfma_f32_16x16x32_bf16((a), (b), (c), 0, 0, 0)

// ---------------- kernel A: fused hmean + weight pack ----------------
__global__ __launch_bounds__(128) void init_kernel(
    const float* __restrict__ h,
    const float* __restrict__ wk1, const float* __restrict__ wk2,
    const float* __restrict__ wk3, const float* __restrict__ wk4,
    const float* __restrict__ wq1, const float* __restrict__ wq2,
    const float* __restrict__ wq3, const float* __restrict__ wq4,
    const float* __restrict__ ihw,
    const float* __restrict__ r1ih, const float* __restrict__ r1hh,
    const float* __restrict__ r2ih, const float* __restrict__ r2hh,
    unsigned short* __restrict__ wbf, unsigned short* __restrict__ wgru,
    unsigned short* __restrict__ wqp, unsigned short* __restrict__ wihb,
    float* __restrict__ F)
{
    if (blockIdx.x < 2048) {          // hmean partials
        int b = blockIdx.x >> 3, seg = blockIdx.x & 7, d = threadIdx.x;
        const float* base = h + ((size_t)(b * GS + seg * 128)) * DD + d;
        float s = 0.0f;
#pragma unroll 8
        for (int r = 0; r < 128; r++) s += base[(size_t)r * DD];
        F[FH_HM + b * 1024 + seg * 128 + d] = s;
        return;
    }
    int tid = (blockIdx.x - 2048) * 128 + threadIdx.x;
    int nth = 128 * 128;
    const float* wks[4]  = {wk1, wk2, wk3, wk4};
    const float* rws[4]  = {r1ih, r1hh, r2ih, r2hh};
    const float* wqs2[4] = {wq1, wq3, wq2, wq4};

    for (int e = tid; e < 65536; e += nth)            // W_K bf16 [mat][d][k]
        wbf[e] = f2bf(wks[e >> 14][e & 16383]);
    for (int e = tid; e < 196608; e += nth)           // GRU weights row-major
        wgru[e] = f2bf(rws[e / 49152][e % 49152]);
    for (int e = tid; e < 65536; e += nth)            // WQ pairs row-major
        wqp[e] = f2bf(wqs2[e >> 14][e & 16383]);
    for (int e = tid; e < 16384; e += nth)            // init_hidden_W row-major [d][k]
        wihb[e] = f2bf(ihw[e]);
}

// ---------------- kernel B: fused prep + 4 GRU steps + AQ ----------------
// grid 32 = 16 b-tiles x 2 rnns (rho); 256 thr = 4 waves.
__global__ __launch_bounds__(256) void prep_kernel(
    const float* __restrict__ h, const float* __restrict__ ctx2,
    const int* __restrict__ rec, const int* __restrict__ vt,
    const int* __restrict__ la_, const int* __restrict__ fa,
    const float* __restrict__ mW1, const float* __restrict__ mb1,
    const float* __restrict__ mW2, const float* __restrict__ mb2,
    const float* __restrict__ ihb, const float* __restrict__ iq,
    const float* __restrict__ b1ih, const float* __restrict__ b1hh,
    const float* __restrict__ b2ih, const float* __restrict__ b2hh,
    const unsigned short* __restrict__ wgru, const unsigned short* __restrict__ wqp,
    const unsigned short* __restrict__ wihb,
    float* __restrict__ F, int* __restrict__ DESC, float* __restrict__ out)
{
    int rho = blockIdx.x & 1;
    int b0  = (blockIdx.x >> 1) * 16;
    int t = threadIdx.x;
    int lane = t & 63, w = t >> 6, ml = lane & 15, quad = lane >> 4;

    __shared__ float hm[16][128];
    __shared__ float hid[16][8];
    __shared__ float Xs[16][132], Qs[16][132], Qn[16][132];
    __shared__ int sdesc[16][26];

    const float* bih = rho ? b2ih : b1ih;
    const float* bhh = rho ? b2hh : b1hh;

    // (1) hm sums: thread t handles b=t>>4, 8 d's
    {
        int b = t >> 4, dbase = (t & 15) * 8;
#pragma unroll
        for (int e = 0; e < 8; e++) {
            int d = dbase + e;
            float s = 0.0f;
#pragma unroll
            for (int seg = 0; seg < 8; seg++)
                s += F[FH_HM + (b0 + b) * 1024 + seg * 128 + d];
            hm[b][d] = s * (1.0f / 1024.0f);
        }
    }
    // (2) meta hidden: t<128: (b, unit)
    if (t < 128) {
        int b = t >> 3, u = t & 7;
        float a = mb1[u];
        for (int k = 0; k < 9; k++) a += mW1[u * 9 + k] * ctx2[(b0 + b) * 9 + k];
        hid[b][u] = a > 0.0f ? a : 0.0f;
    }
    __syncthreads();

    // (3) V1|V2: 16 outputs per thread
    {
        int b = t >> 4, slot = t & 15;
#pragma unroll
        for (int o = 0; o < 16; o++) {
            int idx = slot + 16 * o;
            float a = mb2[idx];
#pragma unroll
            for (int k = 0; k < 8; k++) a += mW2[idx * 8 + k] * hid[b][k];
            F[FI_V + (b0 + b) * 256 + idx] = a;
        }
    }
    // (4) integer state machine: 16 parallel (one thread per b)
    if (t < 16) {
        int b = b0 + t;
        int ai[4], kal[5] = {0, 0, 0, 0, 0}, kar[4] = {0, 0, 0, 0};
        int idesc[26];
        int stopped = 1, nola = -1, vt0 = 0;
        for (int i = 0; i < 4; i++) {
            idesc[16 + i] = stopped;
            idesc[22 + i] = nola;
            int action = fa[b * 4 + i];
            if (i > 0 && stopped) action = ai[0];
            int nona = rec[b * GS + action];
            ai[i] = action;
            if (stopped) kal[i] = action;
            int jprev = (i + 3) & 3;
            if (!stopped) kar[jprev] = action;
            kal[i + 1] = nona;
            int hit = (action == nola) ? 1 : 0;
            int st = (i > 0) ? (stopped | hit) : hit;
            if (st) kal[i] = kal[(i + 4) % 5];
            if (st) kar[i] = kar[jprev];
            if (i == 0) vt0 = vt[b * GS + action];
            idesc[0 + i]  = action;
            idesc[4 + i]  = (vt[b * GS + action] - vt0) & (GS - 1);
            idesc[8 + i]  = st;
            idesc[12 + i] = (!st && (nona == ai[0])) ? 1 : 0;
            nola = st ? -1 : nona;
            stopped = st;
        }
        if (!stopped) kar[3] = kal[4];
        idesc[20] = la_[b];
        idesc[21] = vt0;
        int* dd = DESC + b * 32;
        for (int c = 0; c < 26; c++) { dd[c] = idesc[c]; sdesc[t][c] = idesc[c]; }
        float* oa = out + b * 12;
        for (int c = 0; c < 4; c++) {
            oa[c]     = (float)ai[c];
            oa[4 + c] = (float)kal[c];
            oa[8 + c] = (float)kar[c];
        }
    }
    // (5) q0 = hm @ ihw^T + ihb via MFMA (wave w -> n-tiles 2w, 2w+1)
    {
        bf16x8_t am[4];
#pragma unroll
        for (int kt = 0; kt < 4; kt++) {
            int k0 = kt * 32 + quad * 8;
            bf16x8_t a;
#pragma unroll
            for (int e = 0; e < 8; e++) a[e] = (short)f2bf(hm[ml][k0 + e]);
            am[kt] = a;
        }
#pragma unroll
        for (int nt2 = 0; nt2 < 2; nt2++) {
            int n = (w * 2 + nt2) * 16 + ml;
            const unsigned short* wb = wihb + (size_t)n * 128 + quad * 8;
            f32x4_t acc = {0.f, 0.f, 0.f, 0.f};
#pragma unroll
            for (int kt = 0; kt < 4; kt++)
                acc = MFMA16(am[kt], *(const bf16x8_t*)(wb + kt * 32), acc);
            float bias = ihb[n];
#pragma unroll
            for (int r_ = 0; r_ < 4; r_++)
                Qs[quad * 4 + r_][n] = acc[r_] + bias;
        }
    }
    __syncthreads();

    // (6) 4 GRU steps + AQ projections
    int row = t >> 4, d0 = (t & 15) * 8;
    for (int i = 0; i < 4; i++) {
        {
            if (i > 0) {
#pragma unroll
                for (int e = 0; e < 8; e++) Qs[row][d0 + e] = Qn[row][d0 + e];
            }
            const float* xsrc;
            if (i == 0) xsrc = iq + d0;
            else {
                int a = sdesc[row][i - 1];
                int srcrow;
                if (rho == 0) srcrow = a;
                else {
                    int sE = sdesc[row][16 + (i - 1)];
                    int nl = sdesc[row][22 + (i - 1)];
                    srcrow = sE ? a : (nl & (GS - 1));
                }
                xsrc = h + ((size_t)((b0 + row) * GS + srcrow)) * DD + d0;
            }
#pragma unroll
            for (int e = 0; e < 8; e++) Xs[row][d0 + e] = xsrc[e];
        }
        __syncthreads();

        bf16x8_t ax[4], aq[4];
#pragma unroll
        for (int kt = 0; kt < 4; kt++) {
            int k0 = kt * 32 + quad * 8;
            bf16x8_t a, bb;
#pragma unroll
            for (int e = 0; e < 8; e++) {
                a[e]  = (short)f2bf(Xs[ml][k0 + e]);
                bb[e] = (short)f2bf(Qs[ml][k0 + e]);
            }
            ax[kt] = a; aq[kt] = bb;
        }
        f32x4_t gi[3][2], gh[3][2];
#pragma unroll
        for (int gate = 0; gate < 3; gate++)
#pragma unroll
            for (int sub = 0; sub < 2; sub++) {
                int n = gate * 128 + w * 32 + sub * 16 + ml;
                const unsigned short* wi = wgru + ((size_t)((rho * 2 + 0) * 384 + n)) * 128 + quad * 8;
                const unsigned short* wh = wgru + ((size_t)((rho * 2 + 1) * 384 + n)) * 128 + quad * 8;
                f32x4_t ai = {0.f, 0.f, 0.f, 0.f}, ah = {0.f, 0.f, 0.f, 0.f};
#pragma unroll
                for (int kt = 0; kt < 4; kt++) {
                    ai = MFMA16(ax[kt], *(const bf16x8_t*)(wi + kt * 32), ai);
                    ah = MFMA16(aq[kt], *(const bf16x8_t*)(wh + kt * 32), ah);
                }
                gi[gate][sub] = ai; gh[gate][sub] = ah;
            }
#pragma unroll
        for (int sub = 0; sub < 2; sub++) {
            int d = w * 32 + sub * 16 + ml;
            float bir = bih[d], biz = bih[128 + d], bin_ = bih[256 + d];
            float bhr = bhh[d], bhz = bhh[128 + d], bhn = bhh[256 + d];
#pragma unroll
            for (int r_ = 0; r_ < 4; r_++) {
                int brow = quad * 4 + r_;
                float r = sigm2(gi[0][sub][r_] + bir + gh[0][sub][r_] + bhr);
                float z = sigm2(gi[1][sub][r_] + biz + gh[1][sub][r_] + bhz);
                float n = tanh2(gi[2][sub][r_] + bin_ + r * (gh[2][sub][r_] + bhn));
                float qo = Qs[brow][d];
                Qn[brow][d] = fmaf(z, qo - n, n);
            }
        }
        __syncthreads();

        bf16x8_t aqn[4];
#pragma unroll
        for (int kt = 0; kt < 4; kt++) {
            int k0 = kt * 32 + quad * 8;
            bf16x8_t a;
#pragma unroll
            for (int e = 0; e < 8; e++) a[e] = (short)f2bf(Qn[ml][k0 + e]);
            aqn[kt] = a;
        }
#pragma unroll
        for (int nt = 0; nt < 4; nt++) {
            int n = w * 64 + nt * 16 + ml;
            const unsigned short* wq = wqp + ((size_t)(rho * 256 + n)) * 128 + quad * 8;
            f32x4_t acc = {0.f, 0.f, 0.f, 0.f};
#pragma unroll
            for (int kt = 0; kt < 4; kt++)
                acc = MFMA16(aqn[kt], *(const bf16x8_t*)(wq + kt * 32), acc);
            int sel = rho * 2 + (n >> 7);
            int dd2 = n & 127;
#pragma unroll
            for (int r_ = 0; r_ < 4; r_++) {
                int b2 = b0 + quad * 4 + r_;
                F[FJ_AQB + b2 * 2048 + dd2 * 16 + i * 4 + sel] = acc[r_];
            }
        }
        __syncthreads();
    }
}

// ---------------- kernel C: score, mat-split waves ----------------
// grid 512 = (b, g-half); 1024 thr = 16 waves.
// wave w: hw = w>>3 selects {K1,K3,V1,(a1,b1)} or {K2,K4,V2,(a2,b2)};
// ds = w&7 -> d-cols [16ds,16ds+16). B-frags 32 VGPR, truly resident.
#define SROW 136
__global__ __launch_bounds__(1024, 4) void score_kernel(
    const float* __restrict__ h, const unsigned short* __restrict__ wbf,
    float* __restrict__ F)
{
    int b = blockIdx.x >> 1, gh = blockIdx.x & 1;
    int t = threadIdx.x;
    int lane = t & 63, w = t >> 6;
    int ml = lane & 15, quad = lane >> 4;
    int hw = w >> 3, ds = w & 7;
    int dg = ds * 16 + ml;

    __shared__ unsigned short stg[2][16 * SROW];
    __shared__ float red[2][64];

    // persistent per-lane preloads (loop-invariant)
    int matA = hw ? 1 : 0;   // K2 : K1  (additive)
    int matM = hw ? 3 : 2;   // K4 : K3  (multiplicative)
    bf16x8_t bfr[2][4];
#pragma unroll
    for (int kt = 0; kt < 4; kt++) {
        bfr[0][kt] = *(const bf16x8_t*)(wbf + ((size_t)(matA * 128 + dg)) * 128 + kt * 32 + quad * 8);
        bfr[1][kt] = *(const bf16x8_t*)(wbf + ((size_t)(matM * 128 + dg)) * 128 + kt * 32 + quad * 8);
    }
    float V = F[FI_V + b * 256 + hw * 128 + dg];
    f32x2_t Vs = {V, V};
    const float* AQ = F + FJ_AQB + b * 2048 + dg * 16 + hw * 2;
    f32x2_t aA[2], bB[2];
#pragma unroll
    for (int p = 0; p < 2; p++) {
        f32x2_t q0 = *(const f32x2_t*)(AQ + (2 * p) * 4);
        f32x2_t q1 = *(const f32x2_t*)(AQ + (2 * p + 1) * 4);
        aA[p] = (f32x2_t){q0[0], q1[0]};
        bB[p] = (f32x2_t){q0[1], q1[1]};
    }

    int srow = t >> 6;          // 0..15
    int scol = (t & 63) * 2;    // 0..126 (floats)
    const float* hbase = h + ((size_t)(b * GS + gh * 512 + srow)) * DD + scol;

    if (t < 128) red[t >> 6][t & 63] = 0.0f;

    f32x2_t pre = *(const f32x2_t*)hbase;
    {
        unsigned int pk = (unsigned int)f2bf(pre[0]) | ((unsigned int)f2bf(pre[1]) << 16);
        *(unsigned int*)&stg[0][srow * SROW + scol] = pk;
    }
    __syncthreads();

    for (int tl = 0; tl < 32; tl++) {
        if (tl + 1 < 32)
            pre = *(const f32x2_t*)(hbase + (size_t)(tl + 1) * 16 * DD);

        const unsigned short* sb = stg[tl & 1];
        f32x4_t c[2];
        c[0] = (f32x4_t){0.f, 0.f, 0.f, 0.f};
        c[1] = (f32x4_t){0.f, 0.f, 0.f, 0.f};
#pragma unroll
        for (int kt = 0; kt < 4; kt++) {
            bf16x8_t af = *(const bf16x8_t*)(sb + ml * SROW + kt * 32 + quad * 8);
            c[0] = MFMA16(af, bfr[0][kt], c[0]);
            c[1] = MFMA16(af, bfr[1][kt], c[1]);
        }
        // combine: v[r*4+j] = tanh~(cA + a_j + cM*b_j) * V  (C/D: col=ml=d, row=quad*4+r=g)
        float v[16];
#pragma unroll
        for (int r = 0; r < 4; r++) {
            f32x2_t c0s = {c[0][r], c[0][r]};
            f32x2_t c1s = {c[1][r], c[1][r]};
#pragma unroll
            for (int p = 0; p < 2; p++) {
                f32x2_t y = c0s + aA[p] + c1s * bB[p];
                f32x2_t s = y * y + (f32x2_t){1.0f, 1.0f};
                f32x2_t rr_ = {__builtin_amdgcn_rsqf(s[0]), __builtin_amdgcn_rsqf(s[1])};
                f32x2_t tv = y * rr_ * Vs;
                v[r * 4 + 2 * p]     = tv[0];
                v[r * 4 + 2 * p + 1] = tv[1];
            }
        }
        // butterfly: lane ml ends with sum over 16 ml-lanes of v[ml]
        {
            int bs = ml & 1;
#pragma unroll
            for (int i = 0; i < 8; i++) {
                float lo = v[2 * i], hi = v[2 * i + 1];
                float send = bs ? lo : hi;
                float recv = __shfl_xor(send, 1);
                v[i] = (bs ? hi : lo) + recv;
            }
        }
        {
            int bs = (ml >> 1) & 1;
#pragma unroll
            for (int i = 0; i < 4; i++) {
                float lo = v[2 * i], hi = v[2 * i + 1];
                float send = bs ? lo : hi;
                float recv = __shfl_xor(send, 2);
                v[i] = (bs ? hi : lo) + recv;
            }
        }
        {
            int bs = (ml >> 2) & 1;
#pragma unroll
            for (int i = 0; i < 2; i++) {
                float lo = v[2 * i], hi = v[2 * i + 1];
                float send = bs ? lo : hi;
                float recv = __shfl_xor(send, 4);
                v[i] = (bs ? hi : lo) + recv;
            }
        }
        {
            int bs = (ml >> 3) & 1;
            float lo = v[0], hi = v[1];
            float send = bs ? lo : hi;
            float recv = __shfl_xor(send, 8);
            v[0] = (bs ? hi : lo) + recv;
        }
        atomicAdd(&red[tl & 1][quad * 16 + ml], v[0]);

        if (tl + 1 < 32) {
            unsigned int pk = (unsigned int)f2bf(pre[0]) | ((unsigned int)f2bf(pre[1]) << 16);
            *(unsigned int*)&stg[(tl + 1) & 1][srow * SROW + scol] = pk;
        }
        __syncthreads();
        if (t < 64) {
            int j = t >> 4, gp = t & 15;
            int ridx = (gp >> 2) * 16 + (gp & 3) * 4 + j;
            float val = red[tl & 1][ridx];
            red[tl & 1][ridx] = 0.0f;
            int g = gh * 512 + tl * 16 + gp;
            F[FK_RES + (size_t)b * 4096 + j * 1024 + g] = val;
        }
    }
}

// ---------------- kernel D: masked log-softmax + ll ----------------
__global__ __launch_bounds__(256) void finalize_kernel(
    const float* __restrict__ F, const int* __restrict__ DESC,
    const int* __restrict__ vt, float* __restrict__ out)
{
    int b = blockIdx.x, t = threadIdx.x;
    const int* dd = DESC + b * 32;
    int act0 = dd[0], la = dd[20], vt0 = dd[21];
    __shared__ float sred[8];
    __shared__ float schosen;
    float ll = 0.0f;

    int vtts[4];
#pragma unroll
    for (int q = 0; q < 4; q++) {
        int g = t + q * 256;
        vtts[q] = (vt[b * GS + g] - vt0) & (GS - 1);
    }

    for (int j = 0; j < 4; j++) {
        int aj = dd[j];
        float lg[4];
#pragma unroll
        for (int q = 0; q < 4; q++) {
            int g = t + q * 256;
            bool neg;
            if (j == 0) {
                neg = (g == la);
            } else {
                int p = j - 1;
                neg = (vtts[q] <= dd[4 + p]) || (p == 0 && vtts[q] > GS - 2);
                if (dd[8 + p] && g == dd[p]) neg = false;
                if (dd[12 + p] && g == act0) neg = false;
            }
            float r = F[FK_RES + (size_t)b * 4096 + j * 1024 + g];
            float vv = neg ? NEGV : 6.0f * rtanh(r);
            lg[q] = vv;
            if (g == aj) schosen = vv;
        }
        float mx = fmaxf(fmaxf(lg[0], lg[1]), fmaxf(lg[2], lg[3]));
#pragma unroll
        for (int o = 1; o < 64; o <<= 1) mx = fmaxf(mx, __shfl_xor(mx, o));
        if ((t & 63) == 0) sred[t >> 6] = mx;
        __syncthreads();
        mx = fmaxf(fmaxf(sred[0], sred[1]), fmaxf(sred[2], sred[3]));
        float sm = 0.0f;
#pragma unroll
        for (int q = 0; q < 4; q++) sm += __expf(lg[q] - mx);
#pragma unroll
        for (int o = 1; o < 64; o <<= 1) sm += __shfl_xor(sm, o);
        if ((t & 63) == 0) sred[4 + (t >> 6)] = sm;
        __syncthreads();
        if (t == 0) {
            float tot = sred[4] + sred[5] + sred[6] + sred[7];
            float lse = mx + logf(tot);
            int gate = (j == 0) || (!dd[16 + j]);
            if (gate) ll += schosen - lse;
        }
        __syncthreads();
    }
    if (t == 0) out[3072 + b] = ll;
}

extern "C" void kernel_launch(void* const* d_in, const int* in_sizes, int n_in,
                              void* d_out, int out_size, void* d_ws, size_t ws_size,
                              hipStream_t stream)
{
    (void)in_sizes; (void)n_in; (void)out_size; (void)ws_size;
    const float* h    = (const float*)d_in[0];
    const float* ctx2 = (const float*)d_in[1];
    const int*   rec  = (const int*)d_in[2];
    const int*   vtm  = (const int*)d_in[3];
    const int*   la   = (const int*)d_in[4];
    const int*   fa   = (const int*)d_in[5];
    const float* wk1 = (const float*)d_in[7];
    const float* wk2 = (const float*)d_in[8];
    const float* wk3 = (const float*)d_in[9];
    const float* wk4 = (const float*)d_in[10];
    const float* wq1 = (const float*)d_in[11];
    const float* wq2 = (const float*)d_in[12];
    const float* wq3 = (const float*)d_in[13];
    const float* wq4 = (const float*)d_in[14];
    const float* mW1 = (const float*)d_in[15];
    const float* mb1 = (const float*)d_in[16];
    const float* mW2 = (const float*)d_in[17];
    const float* mb2 = (const float*)d_in[18];
    const float* ihw = (const float*)d_in[19];
    const float* ihb = (const float*)d_in[20];
    const float* iq  = (const float*)d_in[21];
    const float* r1ih = (const float*)d_in[22];
    const float* r1hh = (const float*)d_in[23];
    const float* b1ih = (const float*)d_in[24];
    const float* b1hh = (const float*)d_in[25];
    const float* r2ih = (const float*)d_in[26];
    const float* r2hh = (const float*)d_in[27];
    const float* b2ih = (const float*)d_in[28];
    const float* b2hh = (const float*)d_in[29];

    unsigned short* wbf  = (unsigned short*)d_ws;
    unsigned short* wgru = (unsigned short*)((char*)d_ws + WGRU_OFF_BYTES);
    unsigned short* wqp  = (unsigned short*)((char*)d_ws + WQP_OFF_BYTES);
    unsigned short* wihb = (unsigned short*)((char*)d_ws + WIHB_OFF_BYTES);
    float* F   = (float*)((char*)d_ws + F_OFF_BYTES);
    int* DESC  = (int*)((char*)d_ws + DESC_OFF_BYTES);
    float* out = (float*)d_out;

    init_kernel<<<dim3(2176), dim3(128), 0, stream>>>(h, wk1, wk2, wk3, wk4,
                                                      wq1, wq2, wq3, wq4, ihw,
                                                      r1ih, r1hh, r2ih, r2hh,
                                                      wbf, wgru, wqp, wihb, F);
    prep_kernel<<<dim3(32), dim3(256), 0, stream>>>(h, ctx2, rec, vtm, la, fa,
                                                    mW1, mb1, mW2, mb2, ihb, iq,
                                                    b1ih, b1hh, b2ih, b2hh,
                                                    wgru, wqp, wihb, F, DESC, out);
    score_kernel<<<dim3(512), dim3(1024), 0, stream>>>(h, wbf, F);
    finalize_kernel<<<dim3(256), dim3(256), 0, stream>>>(F, DESC, vtm, out);
}

// Round 5
// 404.369 us; speedup vs baseline: 1.1513x; 1.1513x over previous
//
#include <hip/hip_runtime.h>
#include <hip/hip_bf16.h>
#include <math.h>

#define GS 1024
#define BSZ 256
#define DD 128
#define NEGV -1e30f

typedef __attribute__((ext_vector_type(8))) short bf16x8_t;
typedef __attribute__((ext_vector_type(4))) float f32x4_t;
typedef __attribute__((ext_vector_type(2))) float f32x2_t;

// ---- workspace layout (bytes) ----
#define WGRU_OFF_BYTES 131072
#define WQP_OFF_BYTES  524288
#define WIHB_OFF_BYTES 655360
#define F_OFF_BYTES    688128
// float offsets inside F:
#define FH_HM   0        // 262144  h-mean partials [b][seg][d]
#define FI_V    262144   // 65536   [b][256] V1|V2
#define FJ_AQB  327680   // 524288  [b][d][j][sel]  sel = {a1,b1,a2,b2}
#define FK_RES  851968   // 1048576 [b][j][g]
#define F_TOTAL 1900544
#define DESC_OFF_BYTES (F_OFF_BYTES + F_TOTAL * 4)   // int [b][32]

__device__ __forceinline__ float rtanh(float x) {
    float s = fmaf(x, x, 1.0f);
    return x * __builtin_amdgcn_rsqf(s);
}
__device__ __forceinline__ float tanh2(float x) {
    float e = __expf(x + x);
    return fmaf(-2.0f, __builtin_amdgcn_rcpf(e + 1.0f), 1.0f);
}
__device__ __forceinline__ float sigm2(float x) {
    return __builtin_amdgcn_rcpf(1.0f + __expf(-x));
}
__device__ __forceinline__ unsigned short f2bf(float f) {
    union { float f; unsigned u; } v; v.f = f;
    unsigned u = v.u;
    return (unsigned short)((u + 0x7fffu + ((u >> 16) & 1u)) >> 16);
}
#define MFMA16(a, b, c) __builtin_amdgcn_mfma_f32_16x16x32_bf16((a), (b), (c), 0, 0, 0)

// ---------------- kernel A: fused hmean + weight pack ----------------
__global__ __launch_bounds__(128) void init_kernel(
    const float* __restrict__ h,
    const float* __restrict__ wk1, const float* __restrict__ wk2,
    const float* __restrict__ wk3, const float* __restrict__ wk4,
    const float* __restrict__ wq1, const float* __restrict__ wq2,
    const float* __restrict__ wq3, const float* __restrict__ wq4,
    const float* __restrict__ ihw,
    const float* __restrict__ r1ih, const float* __restrict__ r1hh,
    const float* __restrict__ r2ih, const float* __restrict__ r2hh,
    unsigned short* __restrict__ wbf, unsigned short* __restrict__ wgru,
    unsigned short* __restrict__ wqp, unsigned short* __restrict__ wihb,
    float* __restrict__ F)
{
    if (blockIdx.x < 2048) {          // hmean partials
        int b = blockIdx.x >> 3, seg = blockIdx.x & 7, d = threadIdx.x;
        const float* base = h + ((size_t)(b * GS + seg * 128)) * DD + d;
        float s = 0.0f;
#pragma unroll 8
        for (int r = 0; r < 128; r++) s += base[(size_t)r * DD];
        F[FH_HM + b * 1024 + seg * 128 + d] = s;
        return;
    }
    int tid = (blockIdx.x - 2048) * 128 + threadIdx.x;
    int nth = 128 * 128;
    const float* wks[4]  = {wk1, wk2, wk3, wk4};
    const float* rws[4]  = {r1ih, r1hh, r2ih, r2hh};
    const float* wqs2[4] = {wq1, wq3, wq2, wq4};

    for (int e = tid; e < 65536; e += nth)            // W_K bf16 [mat][d][k]
        wbf[e] = f2bf(wks[e >> 14][e & 16383]);
    for (int e = tid; e < 196608; e += nth)           // GRU weights row-major
        wgru[e] = f2bf(rws[e / 49152][e % 49152]);
    for (int e = tid; e < 65536; e += nth)            // WQ pairs row-major
        wqp[e] = f2bf(wqs2[e >> 14][e & 16383]);
    for (int e = tid; e < 16384; e += nth)            // init_hidden_W row-major [d][k]
        wihb[e] = f2bf(ihw[e]);
}

// ---------------- kernel B: fused prep + 4 GRU steps + AQ ----------------
// grid 32 = 16 b-tiles x 2 rnns (rho); 512 thr = 8 waves.
// Wave w owns d-slice [16w,16w+16); lane (quad,ml) owns (b=quad*4+r, d=16w+ml),
// GRU hidden state in registers across all 4 steps; X rows prefetched to LDS.
__global__ __launch_bounds__(512) void prep_kernel(
    const float* __restrict__ h, const float* __restrict__ ctx2,
    const int* __restrict__ rec, const int* __restrict__ vt,
    const int* __restrict__ la_, const int* __restrict__ fa,
    const float* __restrict__ mW1, const float* __restrict__ mb1,
    const float* __restrict__ mW2, const float* __restrict__ mb2,
    const float* __restrict__ ihb, const float* __restrict__ iq,
    const float* __restrict__ b1ih, const float* __restrict__ b1hh,
    const float* __restrict__ b2ih, const float* __restrict__ b2hh,
    const unsigned short* __restrict__ wgru, const unsigned short* __restrict__ wqp,
    const unsigned short* __restrict__ wihb,
    float* __restrict__ F, int* __restrict__ DESC, float* __restrict__ out)
{
    int rho = blockIdx.x & 1;
    int b0  = (blockIdx.x >> 1) * 16;
    int t = threadIdx.x;
    int lane = t & 63, w = t >> 6, ml = lane & 15, quad = lane >> 4;
    int dloc = w * 16 + ml;     // this lane's d

    __shared__ __attribute__((aligned(16))) unsigned short hmb[16][136];
    __shared__ __attribute__((aligned(16))) unsigned short Xall[4][16][136];
    __shared__ __attribute__((aligned(16))) unsigned short Qb[2][16][136];
    __shared__ float hid[16][8];
    __shared__ int sdesc[16][26];

    const float* bih = rho ? b2ih : b1ih;
    const float* bhh = rho ? b2hh : b1hh;

    // ---- phase 0: hm sums, meta hidden, int machine (independent) ----
#pragma unroll
    for (int k = 0; k < 4; k++) {
        int e = t + 512 * k;               // 2048 = 16b x 128d
        int b = e >> 7, d = e & 127;
        float s = 0.0f;
#pragma unroll
        for (int seg = 0; seg < 8; seg++)
            s += F[FH_HM + (b0 + b) * 1024 + seg * 128 + d];
        hmb[b][d] = f2bf(s * (1.0f / 1024.0f));
    }
    if (t < 128) {
        int b = t >> 3, u = t & 7;
        float a = mb1[u];
        for (int k = 0; k < 9; k++) a += mW1[u * 9 + k] * ctx2[(b0 + b) * 9 + k];
        hid[b][u] = a > 0.0f ? a : 0.0f;
    }
    if (t >= 128 && t < 144) {
        int tb = t - 128;
        int b = b0 + tb;
        int ai[4], kal[5] = {0, 0, 0, 0, 0}, kar[4] = {0, 0, 0, 0};
        int idesc[26];
        int stopped = 1, nola = -1, vt0 = 0;
        for (int i = 0; i < 4; i++) {
            idesc[16 + i] = stopped;
            idesc[22 + i] = nola;
            int action = fa[b * 4 + i];
            if (i > 0 && stopped) action = ai[0];
            int nona = rec[b * GS + action];
            ai[i] = action;
            if (stopped) kal[i] = action;
            int jprev = (i + 3) & 3;
            if (!stopped) kar[jprev] = action;
            kal[i + 1] = nona;
            int hit = (action == nola) ? 1 : 0;
            int st = (i > 0) ? (stopped | hit) : hit;
            if (st) kal[i] = kal[(i + 4) % 5];
            if (st) kar[i] = kar[jprev];
            if (i == 0) vt0 = vt[b * GS + action];
            idesc[0 + i]  = action;
            idesc[4 + i]  = (vt[b * GS + action] - vt0) & (GS - 1);
            idesc[8 + i]  = st;
            idesc[12 + i] = (!st && (nona == ai[0])) ? 1 : 0;
            nola = st ? -1 : nona;
            stopped = st;
        }
        if (!stopped) kar[3] = kal[4];
        idesc[20] = la_[b];
        idesc[21] = vt0;
        int* dd = DESC + b * 32;
        for (int c = 0; c < 26; c++) { dd[c] = idesc[c]; sdesc[tb][c] = idesc[c]; }
        float* oa = out + b * 12;
        for (int c = 0; c < 4; c++) {
            oa[c]     = (float)ai[c];
            oa[4 + c] = (float)kal[c];
            oa[8 + c] = (float)kar[c];
        }
    }
    __syncthreads();

    // ---- phase 1: V, X-prefetch (needs sdesc), q0 (needs hmb) ----
#pragma unroll
    for (int k = 0; k < 8; k++) {
        int o = t + 512 * k;               // 4096 = 16b x 256
        int b = o >> 8, idx = o & 255;
        float a = mb2[idx];
#pragma unroll
        for (int u = 0; u < 8; u++) a += mW2[idx * 8 + u] * hid[b][u];
        F[FI_V + (b0 + b) * 256 + idx] = a;
    }
    for (int e = t; e < 2048; e += 512) {  // step 0: iq broadcast to 16 rows
        int row = e >> 7, d = e & 127;
        Xall[0][row][d] = f2bf(iq[d]);
    }
    for (int e = t; e < 6144; e += 512) {  // steps 1..3 gathered rows
        int i = (e >> 11) + 1;
        int b = (e >> 7) & 15, d = e & 127;
        int a = sdesc[b][i - 1];
        int srcrow = a;
        if (rho) {
            int sE = sdesc[b][16 + (i - 1)];
            int nl = sdesc[b][22 + (i - 1)];
            srcrow = sE ? a : (nl & (GS - 1));
        }
        Xall[i][b][d] = f2bf(h[((size_t)((b0 + b) * GS + srcrow)) * DD + d]);
    }
    // q0 = hm @ ihw^T + ihb (wave w covers n = w*16..w*16+16)
    float qreg[4];
    {
        bf16x8_t am[4];
#pragma unroll
        for (int kt = 0; kt < 4; kt++)
            am[kt] = *(const bf16x8_t*)&hmb[ml][kt * 32 + quad * 8];
        const unsigned short* wb = wihb + (size_t)dloc * 128 + quad * 8;
        f32x4_t acc = {0.f, 0.f, 0.f, 0.f};
#pragma unroll
        for (int kt = 0; kt < 4; kt++)
            acc = MFMA16(am[kt], *(const bf16x8_t*)(wb + kt * 32), acc);
        float bias = ihb[dloc];
#pragma unroll
        for (int r_ = 0; r_ < 4; r_++) {
            qreg[r_] = acc[r_] + bias;
            Qb[0][quad * 4 + r_][dloc] = f2bf(qreg[r_]);
        }
    }
    __syncthreads();

    // ---- phase 2: 4 GRU steps + AQ, one barrier per step ----
    float bir = bih[dloc], biz = bih[128 + dloc], bin_ = bih[256 + dloc];
    float bhr = bhh[dloc], bhz = bhh[128 + dloc], bhn = bhh[256 + dloc];

    for (int i = 0; i < 4; i++) {
        int cur = i & 1;
        bf16x8_t ax[4], aq[4];
#pragma unroll
        for (int kt = 0; kt < 4; kt++) {
            ax[kt] = *(const bf16x8_t*)&Xall[i][ml][kt * 32 + quad * 8];
            aq[kt] = *(const bf16x8_t*)&Qb[cur][ml][kt * 32 + quad * 8];
        }
        f32x4_t gi[3], gh[3];
#pragma unroll
        for (int gate = 0; gate < 3; gate++) {
            int n = gate * 128 + dloc;
            const unsigned short* wi = wgru + ((size_t)((rho * 2 + 0) * 384 + n)) * 128 + quad * 8;
            const unsigned short* wh = wgru + ((size_t)((rho * 2 + 1) * 384 + n)) * 128 + quad * 8;
            f32x4_t ai = {0.f, 0.f, 0.f, 0.f}, ah = {0.f, 0.f, 0.f, 0.f};
#pragma unroll
            for (int kt = 0; kt < 4; kt++) {
                ai = MFMA16(ax[kt], *(const bf16x8_t*)(wi + kt * 32), ai);
                ah = MFMA16(aq[kt], *(const bf16x8_t*)(wh + kt * 32), ah);
            }
            gi[gate] = ai; gh[gate] = ah;
        }
#pragma unroll
        for (int r_ = 0; r_ < 4; r_++) {
            float r = sigm2(gi[0][r_] + bir + gh[0][r_] + bhr);
            float z = sigm2(gi[1][r_] + biz + gh[1][r_] + bhz);
            float n = tanh2(gi[2][r_] + bin_ + r * (gh[2][r_] + bhn));
            qreg[r_] = fmaf(z, qreg[r_] - n, n);
            Qb[cur ^ 1][quad * 4 + r_][dloc] = f2bf(qreg[r_]);
        }
        __syncthreads();

        // AQ projection from q' (reads Qb[cur^1])
        bf16x8_t aqn[4];
#pragma unroll
        for (int kt = 0; kt < 4; kt++)
            aqn[kt] = *(const bf16x8_t*)&Qb[cur ^ 1][ml][kt * 32 + quad * 8];
#pragma unroll
        for (int half = 0; half < 2; half++) {
            int nrow = half * 128 + dloc;
            const unsigned short* wq = wqp + ((size_t)(rho * 256 + nrow)) * 128 + quad * 8;
            f32x4_t acc = {0.f, 0.f, 0.f, 0.f};
#pragma unroll
            for (int kt = 0; kt < 4; kt++)
                acc = MFMA16(aqn[kt], *(const bf16x8_t*)(wq + kt * 32), acc);
            int sel = rho * 2 + half;
#pragma unroll
            for (int r_ = 0; r_ < 4; r_++) {
                int b2 = b0 + quad * 4 + r_;
                F[FJ_AQB + b2 * 2048 + dloc * 16 + i * 4 + sel] = acc[r_];
            }
        }
        // no second barrier: next step writes Qb[cur] which was last read before
        // THIS step's barrier; AQ reads Qb[cur^1] which next step only reads.
    }
}

// ---------------- kernel C: score (R3 structure + pinned B + pk rtanh) ------
// grid 512 = (b, g-half); 512 thr = 8 waves; wave w owns d-cols [16w,16w+16).
#define SROW 136
__global__ __launch_bounds__(512, 4) void score_kernel(
    const float* __restrict__ h, const unsigned short* __restrict__ wbf,
    float* __restrict__ F)
{
    int b = blockIdx.x >> 1, gh = blockIdx.x & 1;
    int t = threadIdx.x;
    int lane = t & 63, w = t >> 6;
    int ml = lane & 15, quad = lane >> 4;
    int dg = w * 16 + ml;

    __shared__ __attribute__((aligned(16))) unsigned short stg[2][16 * SROW];
    __shared__ float red[2][64];

    // persistent per-lane B-fragments, pinned so they are NOT rematerialized
    bf16x8_t bfr[4][4];
#pragma unroll
    for (int mat = 0; mat < 4; mat++)
#pragma unroll
        for (int kt = 0; kt < 4; kt++)
            bfr[mat][kt] = *(const bf16x8_t*)(wbf + ((size_t)(mat * 128 + dg)) * 128 + kt * 32 + quad * 8);
#pragma unroll
    for (int mat = 0; mat < 4; mat++)
#pragma unroll
        for (int kt = 0; kt < 4; kt++)
            asm volatile("" : "+v"(bfr[mat][kt]));

    const float* Vb = F + FI_V + b * 256;
    f32x2_t VV = {Vb[dg], Vb[128 + dg]};
    const float* AQ = F + FJ_AQB + b * 2048 + dg * 16;
    f32x2_t aa[4], bb[4];
#pragma unroll
    for (int j = 0; j < 4; j++) {
        f32x4_t q = *(const f32x4_t*)(AQ + j * 4);   // {a1,b1,a2,b2}
        aa[j] = (f32x2_t){q[0], q[2]};
        bb[j] = (f32x2_t){q[1], q[3]};
    }

    int srow = t >> 5;          // 0..15
    int scol = (t & 31) * 4;    // 0..124 (shorts/floats)
    const float* hbase = h + ((size_t)(b * GS + gh * 512 + srow)) * DD + scol;

    if (t < 128) red[t >> 6][t & 63] = 0.0f;

    f32x4_t pre = *(const f32x4_t*)hbase;
    {
        uint2 pk;
        pk.x = (unsigned)f2bf(pre[0]) | ((unsigned)f2bf(pre[1]) << 16);
        pk.y = (unsigned)f2bf(pre[2]) | ((unsigned)f2bf(pre[3]) << 16);
        *(uint2*)&stg[0][srow * SROW + scol] = pk;
    }
    __syncthreads();

    for (int tl = 0; tl < 32; tl++) {
        if (tl + 1 < 32)
            pre = *(const f32x4_t*)(hbase + (size_t)(tl + 1) * 16 * DD);

        const unsigned short* sb = stg[tl & 1];
        f32x4_t c[4];
#pragma unroll
        for (int mat = 0; mat < 4; mat++) c[mat] = (f32x4_t){0.f, 0.f, 0.f, 0.f};
#pragma unroll
        for (int kt = 0; kt < 4; kt++) {
            bf16x8_t af = *(const bf16x8_t*)(sb + ml * SROW + kt * 32 + quad * 8);
#pragma unroll
            for (int mat = 0; mat < 4; mat++)
                c[mat] = MFMA16(af, bfr[mat][kt], c[mat]);
        }
        // packed combine: per (r,j): y = {cK1,cK2} + aa + {cK3,cK4}*bb;
        // v = dot(y*rsq(y*y+1) * VV)
        float v[16];
#pragma unroll
        for (int r = 0; r < 4; r++) {
            f32x2_t cA = {c[0][r], c[1][r]};
            f32x2_t cM = {c[2][r], c[3][r]};
#pragma unroll
            for (int j = 0; j < 4; j++) {
                f32x2_t y = cA + aa[j] + cM * bb[j];
                f32x2_t s = y * y + (f32x2_t){1.0f, 1.0f};
                f32x2_t rs = {__builtin_amdgcn_rsqf(s[0]), __builtin_amdgcn_rsqf(s[1])};
                f32x2_t tv = y * rs * VV;
                v[r * 4 + j] = tv[0] + tv[1];
            }
        }
        // butterfly over 16 ml-lanes: lane ml ends with sum of v[ml]
        {
            int bs = ml & 1;
#pragma unroll
            for (int i = 0; i < 8; i++) {
                float lo = v[2 * i], hi = v[2 * i + 1];
                float send = bs ? lo : hi;
                float recv = __shfl_xor(send, 1);
                v[i] = (bs ? hi : lo) + recv;
            }
        }
        {
            int bs = (ml >> 1) & 1;
#pragma unroll
            for (int i = 0; i < 4; i++) {
                float lo = v[2 * i], hi = v[2 * i + 1];
                float send = bs ? lo : hi;
                float recv = __shfl_xor(send, 2);
                v[i] = (bs ? hi : lo) + recv;
            }
        }
        {
            int bs = (ml >> 2) & 1;
#pragma unroll
            for (int i = 0; i < 2; i++) {
                float lo = v[2 * i], hi = v[2 * i + 1];
                float send = bs ? lo : hi;
                float recv = __shfl_xor(send, 4);
                v[i] = (bs ? hi : lo) + recv;
            }
        }
        {
            int bs = (ml >> 3) & 1;
            float lo = v[0], hi = v[1];
            float send = bs ? lo : hi;
            float recv = __shfl_xor(send, 8);
            v[0] = (bs ? hi : lo) + recv;
        }
        atomicAdd(&red[tl & 1][quad * 16 + ml], v[0]);

        if (tl + 1 < 32) {
            uint2 pk;
            pk.x = (unsigned)f2bf(pre[0]) | ((unsigned)f2bf(pre[1]) << 16);
            pk.y = (unsigned)f2bf(pre[2]) | ((unsigned)f2bf(pre[3]) << 16);
            *(uint2*)&stg[(tl + 1) & 1][srow * SROW + scol] = pk;
        }
        __syncthreads();
        if (t < 64) {
            int j = t >> 4, gp = t & 15;
            int ridx = (gp >> 2) * 16 + (gp & 3) * 4 + j;
            float val = red[tl & 1][ridx];
            red[tl & 1][ridx] = 0.0f;
            int g = gh * 512 + tl * 16 + gp;
            F[FK_RES + (size_t)b * 4096 + j * 1024 + g] = val;
        }
    }
}

// ---------------- kernel D: masked log-softmax + ll ----------------
__global__ __launch_bounds__(256) void finalize_kernel(
    const float* __restrict__ F, const int* __restrict__ DESC,
    const int* __restrict__ vt, float* __restrict__ out)
{
    int b = blockIdx.x, t = threadIdx.x;
    const int* dd = DESC + b * 32;
    int act0 = dd[0], la = dd[20], vt0 = dd[21];
    __shared__ float sred[8];
    __shared__ float schosen;
    float ll = 0.0f;

    int vtts[4];
#pragma unroll
    for (int q = 0; q < 4; q++) {
        int g = t + q * 256;
        vtts[q] = (vt[b * GS + g] - vt0) & (GS - 1);
    }

    for (int j = 0; j < 4; j++) {
        int aj = dd[j];
        float lg[4];
#pragma unroll
        for (int q = 0; q < 4; q++) {
            int g = t + q * 256;
            bool neg;
            if (j == 0) {
                neg = (g == la);
            } else {
                int p = j - 1;
                neg = (vtts[q] <= dd[4 + p]) || (p == 0 && vtts[q] > GS - 2);
                if (dd[8 + p] && g == dd[p]) neg = false;
                if (dd[12 + p] && g == act0) neg = false;
            }
            float r = F[FK_RES + (size_t)b * 4096 + j * 1024 + g];
            float vv = neg ? NEGV : 6.0f * rtanh(r);
            lg[q] = vv;
            if (g == aj) schosen = vv;
        }
        float mx = fmaxf(fmaxf(lg[0], lg[1]), fmaxf(lg[2], lg[3]));
#pragma unroll
        for (int o = 1; o < 64; o <<= 1) mx = fmaxf(mx, __shfl_xor(mx, o));
        if ((t & 63) == 0) sred[t >> 6] = mx;
        __syncthreads();
        mx = fmaxf(fmaxf(sred[0], sred[1]), fmaxf(sred[2], sred[3]));
        float sm = 0.0f;
#pragma unroll
        for (int q = 0; q < 4; q++) sm += __expf(lg[q] - mx);
#pragma unroll
        for (int o = 1; o < 64; o <<= 1) sm += __shfl_xor(sm, o);
        if ((t & 63) == 0) sred[4 + (t >> 6)] = sm;
        __syncthreads();
        if (t == 0) {
            float tot = sred[4] + sred[5] + sred[6] + sred[7];
            float lse = mx + logf(tot);
            int gate = (j == 0) || (!dd[16 + j]);
            if (gate) ll += schosen - lse;
        }
        __syncthreads();
    }
    if (t == 0) out[3072 + b] = ll;
}

extern "C" void kernel_launch(void* const* d_in, const int* in_sizes, int n_in,
                              void* d_out, int out_size, void* d_ws, size_t ws_size,
                              hipStream_t stream)
{
    (void)in_sizes; (void)n_in; (void)out_size; (void)ws_size;
    const float* h    = (const float*)d_in[0];
    const float* ctx2 = (const float*)d_in[1];
    const int*   rec  = (const int*)d_in[2];
    const int*   vtm  = (const int*)d_in[3];
    const int*   la   = (const int*)d_in[4];
    const int*   fa   = (const int*)d_in[5];
    const float* wk1 = (const float*)d_in[7];
    const float* wk2 = (const float*)d_in[8];
    const float* wk3 = (const float*)d_in[9];
    const float* wk4 = (const float*)d_in[10];
    const float* wq1 = (const float*)d_in[11];
    const float* wq2 = (const float*)d_in[12];
    const float* wq3 = (const float*)d_in[13];
    const float* wq4 = (const float*)d_in[14];
    const float* mW1 = (const float*)d_in[15];
    const float* mb1 = (const float*)d_in[16];
    const float* mW2 = (const float*)d_in[17];
    const float* mb2 = (const float*)d_in[18];
    const float* ihw = (const float*)d_in[19];
    const float* ihb = (const float*)d_in[20];
    const float* iq  = (const float*)d_in[21];
    const float* r1ih = (const float*)d_in[22];
    const float* r1hh = (const float*)d_in[23];
    const float* b1ih = (const float*)d_in[24];
    const float* b1hh = (const float*)d_in[25];
    const float* r2ih = (const float*)d_in[26];
    const float* r2hh = (const float*)d_in[27];
    const float* b2ih = (const float*)d_in[28];
    const float* b2hh = (const float*)d_in[29];

    unsigned short* wbf  = (unsigned short*)d_ws;
    unsigned short* wgru = (unsigned short*)((char*)d_ws + WGRU_OFF_BYTES);
    unsigned short* wqp  = (unsigned short*)((char*)d_ws + WQP_OFF_BYTES);
    unsigned short* wihb = (unsigned short*)((char*)d_ws + WIHB_OFF_BYTES);
    float* F   = (float*)((char*)d_ws + F_OFF_BYTES);
    int* DESC  = (int*)((char*)d_ws + DESC_OFF_BYTES);
    float* out = (float*)d_out;

    init_kernel<<<dim3(2176), dim3(128), 0, stream>>>(h, wk1, wk2, wk3, wk4,
                                                      wq1, wq2, wq3, wq4, ihw,
                                                      r1ih, r1hh, r2ih, r2hh,
                                                      wbf, wgru, wqp, wihb, F);
    prep_kernel<<<dim3(32), dim3(512), 0, stream>>>(h, ctx2, rec, vtm, la, fa,
                                                    mW1, mb1, mW2, mb2, ihb, iq,
                                                    b1ih, b1hh, b2ih, b2hh,
                                                    wgru, wqp, wihb, F, DESC, out);
    score_kernel<<<dim3(512), dim3(512), 0, stream>>>(h, wbf, F);
    finalize_kernel<<<dim3(256), dim3(256), 0, stream>>>(F, DESC, vtm, out);
}